// Round 2
// baseline (131.453 us; speedup 1.0000x reference)
//
#include <hip/hip_runtime.h>
#include <math.h>

#define SEQT 24
#define NSTEP 23
#define NB 64      // batch elements per block
#define BTH 256    // threads per block

// One fully-fused kernel. Each block redundantly computes the per-token
// tables (fp64, same numerics as the verified 4-kernel version) into LDS,
// then scans + applies the head for its 64 batch elements.
//
// Token space: incoming tokens a in [0,66); slot-state b in [0,67), 66 = empty.
__global__ __launch_bounds__(256) void k_fused(
    const int* __restrict__ seqs, const int* __restrict__ query_tok,
    const float* __restrict__ embed,
    const float* __restrict__ wg_w1, const float* __restrict__ wg_b1,
    const float* __restrict__ wg_w2, const float* __restrict__ wg_b2,
    const float* __restrict__ eg_w1, const float* __restrict__ eg_b1,
    const float* __restrict__ eg_w2, const float* __restrict__ eg_b2,
    const float* __restrict__ rh_w1, const float* __restrict__ rh_b1,
    const float* __restrict__ rh_w2, const float* __restrict__ rh_b2,
    float* __restrict__ out)
{
    // rows padded to 33 doubles: stride-32 (256B) gathers would alias all
    // 64 lanes onto one bank pair (32-way conflict); stride-33 -> ~4-way.
    __shared__ double s_u[66 * 33];    // u'[a][j] = ne@eg_w1_top + eg_b1
    __shared__ double s_nb[67 * 33];   // nb[b][j] = embed[b]@eg_w1_bot (row 66 = 0)
    __shared__ double s_h[66 * 33];    // relu(ne@wg_w1+b1)*wg_w2 partials
    __shared__ double s_w[67];         // write-gate sigmoid per token (w[66]=0)
    __shared__ float  sEL[66 * 67];    // evict-gate logit table
    __shared__ int    s_state[NB];
    float* s_qh1 = (float*)s_u;        // overlay after EL: 66*64 fp32
    float* s_ebw = (float*)s_nb;       // overlay after EL: 67*64 fp32

    const int tid = threadIdx.x;

    // ---- phase A1: per-(token, j) fp64 dot products ----
    for (int it = tid; it < 66 * 32; it += BTH) {
        const int a = it >> 5, j = it & 31;
        double u = 0.0, nb = 0.0, h = 0.0;
        for (int k = 0; k < 64; ++k) {
            const double e = (double)embed[a * 64 + k];
            u  += e * (double)eg_w1[k * 32 + j];
            nb += e * (double)eg_w1[(64 + k) * 32 + j];
            h  += e * (double)wg_w1[k * 32 + j];
        }
        s_u[a * 33 + j]  = u + (double)eg_b1[j];
        s_nb[a * 33 + j] = nb;
        double hr = h + (double)wg_b1[j];
        if (hr < 0.0) hr = 0.0;
        s_h[a * 33 + j] = hr * (double)wg_w2[j];
    }
    if (tid < 32) s_nb[66 * 33 + tid] = 0.0;   // empty-slot row
    __syncthreads();

    // ---- phase W: write-gate sigmoid per token ----
    if (tid < 66) {
        double z = (double)wg_b2[0];
        for (int j = 0; j < 32; ++j) z += s_h[tid * 33 + j];
        s_w[tid] = 1.0 / (1.0 + exp(-z));
    } else if (tid == 66) {
        s_w[66] = 0.0;
    }
    __syncthreads();

    // ---- phase EL: evict-gate table EL[a][b] ----
    const double eb2 = (double)eg_b2[0];
    for (int it = tid; it < 66 * 67; it += BTH) {
        const int a = it / 67, b = it - a * 67;
        const double wb = s_w[b];
        double acc = eb2;
        #pragma unroll
        for (int j = 0; j < 32; ++j) {
            const double v = s_u[a * 33 + j] + wb * s_nb[b * 33 + j];
            if (v > 0.0) acc += v * (double)eg_w2[j];
        }
        sEL[it] = (float)acc;   // it == a*67 + b
    }
    __syncthreads();

    // ---- overlap: wave 0 scans; waves 1..3 build head tables ----
    if (tid < NB) {
        const int b = blockIdx.x * NB + tid;
        const int4* rp = (const int4*)(seqs + b * SEQT);   // 96B-aligned rows
        const int4 q0 = rp[0], q1 = rp[1], q2 = rp[2], q3 = rp[3], q4 = rp[4], q5 = rp[5];
        int row[24];
        row[0]=q0.x;  row[1]=q0.y;  row[2]=q0.z;  row[3]=q0.w;
        row[4]=q1.x;  row[5]=q1.y;  row[6]=q1.z;  row[7]=q1.w;
        row[8]=q2.x;  row[9]=q2.y;  row[10]=q2.z; row[11]=q2.w;
        row[12]=q3.x; row[13]=q3.y; row[14]=q3.z; row[15]=q3.w;
        row[16]=q4.x; row[17]=q4.y; row[18]=q4.z; row[19]=q4.w;
        row[20]=q5.x; row[21]=q5.y; row[22]=q5.z; row[23]=q5.w;

        int ts0 = 66, ts1 = 66, ts2 = 66, ts3 = 66;
        #pragma unroll
        for (int t = 0; t < NSTEP; ++t) {
            const int tok  = row[t];            // static after full unroll
            const int base = tok * 67;
            const float e0 = sEL[base + ts0];
            const float e1 = sEL[base + ts1];
            const float e2 = sEL[base + ts2];
            const float e3 = sEL[base + ts3];
            int bi = 0; float best = e0;        // first-of-max == jnp.argmax
            if (e1 > best) { best = e1; bi = 1; }
            if (e2 > best) { best = e2; bi = 2; }
            if (e3 > best) { best = e3; bi = 3; }
            ts0 = (bi == 0) ? tok : ts0;
            ts1 = (bi == 1) ? tok : ts1;
            ts2 = (bi == 2) ? tok : ts2;
            ts3 = (bi == 3) ? tok : ts3;
        }
        s_state[tid] = ts0 | (ts1 << 8) | (ts2 << 16) | (ts3 << 24);
    } else {
        if (tid < 128) s_ebw[66 * 64 + (tid - 64)] = 0.0f;   // empty-slot row
        // items: tok = it>>7, c = it&127 (c<64 -> qh1, else ebw).
        // stride 192 keeps each wave-iter on one uniform (tok, half) block.
        for (int it = tid - 64; it < 66 * 128; it += 192) {
            const int tok = it >> 7, c = it & 127;
            float acc = 0.0f;
            if (c < 64) {
                for (int k = 0; k < 64; ++k)
                    acc += embed[tok * 64 + k] * rh_w1[k * 64 + c];
                s_qh1[tok * 64 + c] = acc + rh_b1[c];
            } else {
                const int o = c - 64;
                for (int k = 0; k < 64; ++k)
                    acc += embed[tok * 64 + k] * rh_w1[(64 + k) * 64 + o];
                s_ebw[tok * 64 + o] = 0.25f * (float)s_w[tok] * acc;
            }
        }
    }
    __syncthreads();

    // ---- head: 16 batch elems per wave ----
    const int lane = tid & 63;
    const int wv   = tid >> 6;

    float w2c[64];                      // lane o holds rh_w2[:, o]
    #pragma unroll
    for (int k = 0; k < 64; ++k) w2c[k] = rh_w2[k * 64 + lane];
    const float rb2 = rh_b2[lane];

    for (int i = 0; i < 16; ++i) {
        const int e  = wv * 16 + i;
        const int bg = blockIdx.x * NB + e;
        const int qt = query_tok[bg];
        const unsigned st = (unsigned)s_state[e];
        const int u0 = st & 255, u1 = (st >> 8) & 255,
                  u2 = (st >> 16) & 255, u3 = st >> 24;
        float h1 = s_qh1[qt * 64 + lane]
                 + s_ebw[u0 * 64 + lane] + s_ebw[u1 * 64 + lane]
                 + s_ebw[u2 * 64 + lane] + s_ebw[u3 * 64 + lane];
        h1 = fmaxf(h1, 0.0f);

        float a0 = rb2, a1 = 0.0f, a2 = 0.0f, a3 = 0.0f;
        #pragma unroll
        for (int k = 0; k < 64; k += 4) {
            const float h0 = __uint_as_float(__builtin_amdgcn_readlane(__float_as_uint(h1), k));
            const float hA = __uint_as_float(__builtin_amdgcn_readlane(__float_as_uint(h1), k + 1));
            const float hB = __uint_as_float(__builtin_amdgcn_readlane(__float_as_uint(h1), k + 2));
            const float hC = __uint_as_float(__builtin_amdgcn_readlane(__float_as_uint(h1), k + 3));
            a0 = fmaf(h0, w2c[k],     a0);
            a1 = fmaf(hA, w2c[k + 1], a1);
            a2 = fmaf(hB, w2c[k + 2], a2);
            a3 = fmaf(hC, w2c[k + 3], a3);
        }
        out[bg * 64 + lane] = (a0 + a1) + (a2 + a3);
    }
}

extern "C" void kernel_launch(void* const* d_in, const int* in_sizes, int n_in,
                              void* d_out, int out_size, void* d_ws, size_t ws_size,
                              hipStream_t stream)
{
    const int*   seqs      = (const int*)  d_in[0];
    const int*   query_tok = (const int*)  d_in[1];
    const float* embed     = (const float*)d_in[2];
    const float* wg_w1     = (const float*)d_in[3];
    const float* wg_b1     = (const float*)d_in[4];
    const float* wg_w2     = (const float*)d_in[5];
    const float* wg_b2     = (const float*)d_in[6];
    const float* eg_w1     = (const float*)d_in[7];
    const float* eg_b1     = (const float*)d_in[8];
    const float* eg_w2     = (const float*)d_in[9];
    const float* eg_b2     = (const float*)d_in[10];
    const float* rh_w1     = (const float*)d_in[11];
    const float* rh_b1     = (const float*)d_in[12];
    const float* rh_w2     = (const float*)d_in[13];
    const float* rh_b2     = (const float*)d_in[14];
    float* out = (float*)d_out;
    const int B = in_sizes[1];   // 16384

    k_fused<<<B / NB, BTH, 0, stream>>>(seqs, query_tok, embed,
                                        wg_w1, wg_b1, wg_w2, wg_b2,
                                        eg_w1, eg_b1, eg_w2, eg_b2,
                                        rh_w1, rh_b1, rh_w2, rh_b2, out);
}

// Round 3
// 33.613 us; speedup vs baseline: 3.9107x; 3.9107x over previous
//
#include <hip/hip_runtime.h>
#include <math.h>

#define SEQT 24
#define NSTEP 23
#define NTOK 66        // real tokens 0..65; sentinel slot-state = 66
#define NSLOT_ST 67    // slot-state alphabet incl. empty

// ---------------- K1: per-token tables, one block per token ----------------
// 224 active threads, each owns ONE 64-MAC fp64 dot product:
//   g0 t[  0, 32): u[a][j]    = embed[a]@eg_w1[0:64,j]   + eg_b1[j]
//   g1 t[ 32, 64): vnwT[j][a] = w(a) * embed[a]@eg_w1[64:128,j]
//   g2 t[ 64, 96): h-partial for write gate w(a)
//   g3 t[ 96,160): qh1[a][c]  = embed[a]@rh_w1[0:64,c]   + rh_b1[c]
//   g4 t[160,224): ebw[a][c]  = 0.25*w(a)*embed[a]@rh_w1[64:128,c]
__global__ __launch_bounds__(256) void k_tables(
    const float* __restrict__ embed,
    const float* __restrict__ wg_w1, const float* __restrict__ wg_b1,
    const float* __restrict__ wg_w2, const float* __restrict__ wg_b2,
    const float* __restrict__ eg_w1, const float* __restrict__ eg_b1,
    const float* __restrict__ rh_w1, const float* __restrict__ rh_b1,
    double* __restrict__ t_u,      // [66][32]
    double* __restrict__ t_vnwT,   // [32][67], col 66 = 0
    float*  __restrict__ t_qh1,    // [66][64]
    float*  __restrict__ t_ebw)    // [66][64]
{
    const int a = blockIdx.x;
    const int t = threadIdx.x;
    __shared__ float  s_e[64];
    __shared__ double s_h[32];
    __shared__ double s_w;

    if (t < 64) s_e[t] = embed[a * 64 + t];
    __syncthreads();

    // select weight column per group (uniform loop, per-lane base/stride)
    const float* wp = nullptr;
    int stride = 32, col = 0;
    if      (t < 32)  { wp = eg_w1;            col = t;       }
    else if (t < 64)  { wp = eg_w1 + 64 * 32;  col = t - 32;  }
    else if (t < 96)  { wp = wg_w1;            col = t - 64;  }
    else if (t < 160) { wp = rh_w1;            col = t - 96;  stride = 64; }
    else if (t < 224) { wp = rh_w1 + 64 * 64;  col = t - 160; stride = 64; }

    double acc = 0.0;
    if (t < 224) {
        #pragma unroll 8
        for (int k = 0; k < 64; ++k)
            acc += (double)s_e[k] * (double)wp[k * stride + col];
    }

    // write-gate partials
    if (t >= 64 && t < 96) {
        const int j = t - 64;
        double hr = acc + (double)wg_b1[j];
        if (hr < 0.0) hr = 0.0;
        s_h[j] = hr * (double)wg_w2[j];
    }
    __syncthreads();
    if (t == 0) {
        double z = (double)wg_b2[0];
        for (int j = 0; j < 32; ++j) z += s_h[j];
        s_w = 1.0 / (1.0 + exp(-z));
    }
    __syncthreads();
    const double w = s_w;

    if      (t < 32)  { t_u[a * 32 + t] = acc + (double)eg_b1[t];
                        if (a == 0) t_vnwT[t * NSLOT_ST + 66] = 0.0; }  // empty col
    else if (t < 64)  { t_vnwT[col * NSLOT_ST + a] = w * acc; }
    else if (t >= 96 && t < 160) { t_qh1[a * 64 + col] = (float)(acc + (double)rh_b1[col]); }
    else if (t >= 160 && t < 224) { t_ebw[a * 64 + col] = (float)(0.25 * w * acc); }
}

// ---------------- K2: evict-gate table EL[66][67] ----------------
__global__ __launch_bounds__(256) void k_el(
    const double* __restrict__ t_u, const double* __restrict__ t_vnwT,
    const float* __restrict__ eg_w2, const float* __restrict__ eg_b2,
    float* __restrict__ t_EL)
{
    const int tid = blockIdx.x * 256 + threadIdx.x;
    if (tid >= NTOK * NSLOT_ST) return;
    const int a = tid / NSLOT_ST;
    const int b = tid - a * NSLOT_ST;
    double acc = (double)eg_b2[0];
    #pragma unroll
    for (int j = 0; j < 32; ++j) {
        const double v = t_u[a * 32 + j] + t_vnwT[j * NSLOT_ST + b];  // coalesced in b
        if (v > 0.0) acc += v * (double)eg_w2[j];
    }
    t_EL[tid] = (float)acc;
}

// ---------------- K3: fused scan + head, 64 batch elems per block ----------------
__global__ __launch_bounds__(256) void k_main(
    const int* __restrict__ seqs, const int* __restrict__ query_tok,
    const float* __restrict__ t_EL, const float* __restrict__ t_qh1,
    const float* __restrict__ t_ebw,
    const float* __restrict__ rh_w2, const float* __restrict__ rh_b2,
    float* __restrict__ out)
{
    __shared__ __align__(16) float sEL[NTOK * NSLOT_ST];   // 17.7 KB
    __shared__ __align__(16) float s_qh1[NTOK * 64];       // 16.9 KB
    __shared__ __align__(16) float s_ebw[NSLOT_ST * 64];   // 17.2 KB
    __shared__ int s_state[64];

    const int tid = threadIdx.x;

    // stage EL (all 256 threads): 4422 floats
    for (int i = tid; i < NTOK * NSLOT_ST; i += 256) sEL[i] = t_EL[i];
    __syncthreads();

    const int wv = tid >> 6, lane = tid & 63;

    if (wv == 0) {
        // ---- scan: one batch element per lane ----
        const int b = blockIdx.x * 64 + lane;
        const int4* rp = (const int4*)(seqs + b * SEQT);   // 96B-aligned rows
        const int4 q0 = rp[0], q1 = rp[1], q2 = rp[2], q3 = rp[3], q4 = rp[4], q5 = rp[5];
        int row[24];
        row[0]=q0.x;  row[1]=q0.y;  row[2]=q0.z;  row[3]=q0.w;
        row[4]=q1.x;  row[5]=q1.y;  row[6]=q1.z;  row[7]=q1.w;
        row[8]=q2.x;  row[9]=q2.y;  row[10]=q2.z; row[11]=q2.w;
        row[12]=q3.x; row[13]=q3.y; row[14]=q3.z; row[15]=q3.w;
        row[16]=q4.x; row[17]=q4.y; row[18]=q4.z; row[19]=q4.w;
        row[20]=q5.x; row[21]=q5.y; row[22]=q5.z; row[23]=q5.w;

        int ts0 = 66, ts1 = 66, ts2 = 66, ts3 = 66;
        #pragma unroll
        for (int t = 0; t < NSTEP; ++t) {
            const int tok  = row[t];            // static after full unroll
            const int base = tok * NSLOT_ST;
            const float e0 = sEL[base + ts0];
            const float e1 = sEL[base + ts1];
            const float e2 = sEL[base + ts2];
            const float e3 = sEL[base + ts3];
            int bi = 0; float best = e0;        // first-of-max == jnp.argmax
            if (e1 > best) { best = e1; bi = 1; }
            if (e2 > best) { best = e2; bi = 2; }
            if (e3 > best) { best = e3; bi = 3; }
            ts0 = (bi == 0) ? tok : ts0;
            ts1 = (bi == 1) ? tok : ts1;
            ts2 = (bi == 2) ? tok : ts2;
            ts3 = (bi == 3) ? tok : ts3;
        }
        s_state[lane] = ts0 | (ts1 << 8) | (ts2 << 16) | (ts3 << 24);
    } else {
        // ---- waves 1-3: stage qh1 + ebw as float4 (2112 vec4s / 192 threads) ----
        const float4* gq = (const float4*)t_qh1;   // 1056 vec4
        const float4* ge = (const float4*)t_ebw;   // 1056 vec4
        float4* sq = (float4*)s_qh1;
        float4* se = (float4*)s_ebw;
        for (int i = tid - 64; i < 2112; i += 192) {
            if (i < 1056) sq[i] = gq[i];
            else          se[i - 1056] = ge[i - 1056];
        }
        if (tid < 128) s_ebw[NTOK * 64 + (tid - 64)] = 0.0f;   // empty-slot row 66
    }
    __syncthreads();

    // ---- head: per-lane-resident rh_w2 column, 16 elems per wave ----
    float w2c[64];                              // lane o holds rh_w2[:, o]
    #pragma unroll
    for (int k = 0; k < 64; ++k) w2c[k] = rh_w2[k * 64 + lane];
    const float rb2 = rh_b2[lane];

    for (int i = 0; i < 16; ++i) {
        const int e  = wv * 16 + i;
        const int bg = blockIdx.x * 64 + e;
        const int qt = query_tok[bg];
        const unsigned st = (unsigned)s_state[e];
        const int u0 = st & 255, u1 = (st >> 8) & 255,
                  u2 = (st >> 16) & 255, u3 = st >> 24;
        float h1 = s_qh1[qt * 64 + lane]
                 + s_ebw[u0 * 64 + lane] + s_ebw[u1 * 64 + lane]
                 + s_ebw[u2 * 64 + lane] + s_ebw[u3 * 64 + lane];
        h1 = fmaxf(h1, 0.0f);

        float a0 = rb2, a1 = 0.0f, a2 = 0.0f, a3 = 0.0f;
        #pragma unroll
        for (int k = 0; k < 64; k += 4) {
            const float h0 = __uint_as_float(__builtin_amdgcn_readlane(__float_as_uint(h1), k));
            const float hA = __uint_as_float(__builtin_amdgcn_readlane(__float_as_uint(h1), k + 1));
            const float hB = __uint_as_float(__builtin_amdgcn_readlane(__float_as_uint(h1), k + 2));
            const float hC = __uint_as_float(__builtin_amdgcn_readlane(__float_as_uint(h1), k + 3));
            a0 = fmaf(h0, w2c[k],     a0);
            a1 = fmaf(hA, w2c[k + 1], a1);
            a2 = fmaf(hB, w2c[k + 2], a2);
            a3 = fmaf(hC, w2c[k + 3], a3);
        }
        out[bg * 64 + lane] = (a0 + a1) + (a2 + a3);
    }
}

extern "C" void kernel_launch(void* const* d_in, const int* in_sizes, int n_in,
                              void* d_out, int out_size, void* d_ws, size_t ws_size,
                              hipStream_t stream)
{
    const int*   seqs      = (const int*)  d_in[0];
    const int*   query_tok = (const int*)  d_in[1];
    const float* embed     = (const float*)d_in[2];
    const float* wg_w1     = (const float*)d_in[3];
    const float* wg_b1     = (const float*)d_in[4];
    const float* wg_w2     = (const float*)d_in[5];
    const float* wg_b2     = (const float*)d_in[6];
    const float* eg_w1     = (const float*)d_in[7];
    const float* eg_b1     = (const float*)d_in[8];
    const float* eg_w2     = (const float*)d_in[9];
    const float* eg_b2     = (const float*)d_in[10];
    const float* rh_w1     = (const float*)d_in[11];
    const float* rh_b1     = (const float*)d_in[12];
    const float* rh_w2     = (const float*)d_in[13];
    const float* rh_b2     = (const float*)d_in[14];
    float* out = (float*)d_out;
    const int B = in_sizes[1];   // 16384

    // workspace layout
    double* t_u    = (double*)d_ws;                    // 66*32 fp64
    double* t_vnwT = t_u + NTOK * 32;                  // 32*67 fp64
    float*  t_qh1  = (float*)(t_vnwT + 32 * NSLOT_ST); // 66*64 fp32
    float*  t_ebw  = t_qh1 + NTOK * 64;                // 66*64 fp32
    float*  t_EL   = t_ebw + NTOK * 64;                // 66*67 fp32

    k_tables<<<NTOK, 256, 0, stream>>>(embed, wg_w1, wg_b1, wg_w2, wg_b2,
                                       eg_w1, eg_b1, rh_w1, rh_b1,
                                       t_u, t_vnwT, t_qh1, t_ebw);
    k_el<<<(NTOK * NSLOT_ST + 255) / 256, 256, 0, stream>>>(t_u, t_vnwT, eg_w2, eg_b2, t_EL);
    k_main<<<B / 64, 256, 0, stream>>>(seqs, query_tok, t_EL, t_qh1, t_ebw,
                                       rh_w2, rh_b2, out);
}